// Round 15
// baseline (137.266 us; speedup 1.0000x reference)
//
#include <hip/hip_runtime.h>
#include <hip/hip_bf16.h>

typedef __attribute__((ext_vector_type(8))) short bf16x8;
typedef __attribute__((ext_vector_type(4))) float f32x4;

// Swizzled byte address for 128-byte rows: XOR row bits into the 16B-slot index.
#define SWZ(row, byteofs) (((row)*128) + ((byteofs) ^ (((row)&7)<<4)))

__device__ __forceinline__ unsigned pk2(float a, float b){
  __hip_bfloat162 h = __float22bfloat162_rn(make_float2(a, b));   // v_cvt_pk_bf16_f32
  unsigned u; __builtin_memcpy(&u, &h, 4);
  return u;
}

__device__ __forceinline__ void gld16(const void* g, void* l){
  __builtin_amdgcn_global_load_lds((const __attribute__((address_space(1))) void*)g,
                                   (__attribute__((address_space(3))) void*)l, 16, 0, 0);
}

union bfpack { bf16x8 v; unsigned u[4]; uint4 q; };

// ================= fused prep kernel =================
// sections by blockIdx.x:
//   [0,2048)      mask -> bitmask (16 keys/thread, int4x4 loads, u16 store)
//   [2048,3072)   W fp32 -> bf16
//   [3072,7168)   K permute (n,L,h*64) f32 -> (n,h,L,64) bf16
//   [7168,9216)   V permute+transpose -> (n,h,64,L) bf16
__global__ __launch_bounds__(256) void prep_kernel(
    const int* __restrict__ mask, unsigned short* __restrict__ bits16,
    const float* __restrict__ W, unsigned short* __restrict__ Wb,
    const float* __restrict__ Ksrc, unsigned short* __restrict__ Kb,
    const float* __restrict__ Vsrc, unsigned short* __restrict__ Vtg)
{
  __shared__ __attribute__((aligned(16))) unsigned short T[64*64];
  int bid = blockIdx.x, tid = threadIdx.x;

  if (bid < 2048){
    // ---- mask bits: thread i covers 16 consecutive mask ints ----
    size_t i = (size_t)bid * 256 + tid;
    const int4* mp = reinterpret_cast<const int4*>(mask) + i * 4;
    int4 a = mp[0], b = mp[1], c = mp[2], d = mp[3];
    unsigned m = 0;
    m |= (a.x!=0) ? 1u<<0 : 0;  m |= (a.y!=0) ? 1u<<1 : 0;
    m |= (a.z!=0) ? 1u<<2 : 0;  m |= (a.w!=0) ? 1u<<3 : 0;
    m |= (b.x!=0) ? 1u<<4 : 0;  m |= (b.y!=0) ? 1u<<5 : 0;
    m |= (b.z!=0) ? 1u<<6 : 0;  m |= (b.w!=0) ? 1u<<7 : 0;
    m |= (c.x!=0) ? 1u<<8 : 0;  m |= (c.y!=0) ? 1u<<9 : 0;
    m |= (c.z!=0) ? 1u<<10 : 0; m |= (c.w!=0) ? 1u<<11 : 0;
    m |= (d.x!=0) ? 1u<<12 : 0; m |= (d.y!=0) ? 1u<<13 : 0;
    m |= (d.z!=0) ? 1u<<14 : 0; m |= (d.w!=0) ? 1u<<15 : 0;
    bits16[i] = (unsigned short)m;
  } else if (bid < 3072){
    // ---- W convert ----
    int i = (bid - 2048) * 256 + tid;
    float4 f = reinterpret_cast<const float4*>(W)[i];
    uint2 o = make_uint2(pk2(f.x, f.y), pk2(f.z, f.w));
    reinterpret_cast<uint2*>(Wb)[i] = o;
  } else if (bid < 7168){
    // ---- K permute ----
    int w = (bid - 3072) * 4 + (tid >> 6);
    int lane = tid & 63;
    int n = w >> 11, h = (w >> 7) & 15, l8 = w & 127;
    int l = l8 * 8 + (lane >> 3);
    int dch = (lane & 7) * 8;
    const float* sp = Ksrc + ((size_t)n * 1024 + l) * 1024 + h * 64 + dch;
    float4 a = *reinterpret_cast<const float4*>(sp);
    float4 b = *reinterpret_cast<const float4*>(sp + 4);
    uint4 o = make_uint4(pk2(a.x,a.y), pk2(a.z,a.w), pk2(b.x,b.y), pk2(b.z,b.w));
    *reinterpret_cast<uint4*>(Kb + (((size_t)n * 16 + h) * 1024 + l) * 64 + dch) = o;
  } else {
    // ---- V permute + transpose ----
    int vb = bid - 7168;                  // 2048 = n(8) x h(16) x ltile(16)
    int n = vb >> 8, h = (vb >> 4) & 15, l0 = (vb & 15) * 64;
    {
      int l = tid >> 2, dseg = tid & 3;
      const float* sp = Vsrc + ((size_t)n * 1024 + l0 + l) * 1024 + h * 64 + dseg * 16;
      float4 f0 = *reinterpret_cast<const float4*>(sp + 0);
      float4 f1 = *reinterpret_cast<const float4*>(sp + 4);
      float4 f2 = *reinterpret_cast<const float4*>(sp + 8);
      float4 f3 = *reinterpret_cast<const float4*>(sp + 12);
      uint4 lo = make_uint4(pk2(f0.x,f0.y), pk2(f0.z,f0.w), pk2(f1.x,f1.y), pk2(f1.z,f1.w));
      uint4 hi = make_uint4(pk2(f2.x,f2.y), pk2(f2.z,f2.w), pk2(f3.x,f3.y), pk2(f3.z,f3.w));
      *reinterpret_cast<uint4*>((char*)T + SWZ(l, dseg*32))      = lo;
      *reinterpret_cast<uint4*>((char*)T + SWZ(l, dseg*32 + 16)) = hi;
    }
    __syncthreads();
    {
      int d = tid >> 2, lseg = tid & 3;
      for (int j = 0; j < 2; ++j){
        bf16x8 wv;
        #pragma unroll
        for (int i = 0; i < 8; ++i){
          int l = lseg*16 + j*8 + i;      // l&7 == i (static per unrolled i)
          wv[i] = *(const short*)((const char*)T + (size_t)l*128 + ((d*2) ^ (i<<4)));
        }
        *reinterpret_cast<bf16x8*>(Vtg + (((size_t)n * 16 + h) * 64 + d) * 1024 + l0 + lseg*16 + j*8) = wv;
      }
    }
  }
}

// ---- flash attention (champion schedule + exp2 fold + mask-word prefetch) ----
// grid: 2048 blocks = (n:8) x (h:16) x (qb:16), 256 threads (4 waves x 16 q-rows)
__global__ __launch_bounds__(256) void attn_kernel(
    const float* __restrict__ Q, const unsigned short* __restrict__ Kb,
    const unsigned short* __restrict__ Vtg, const unsigned* __restrict__ bits,
    unsigned short* __restrict__ Obf)
{
  __shared__ __attribute__((aligned(16))) unsigned short Kt[2][64*64];   // [key][d], swizzled
  __shared__ __attribute__((aligned(16))) unsigned short Vt[2][64*64];   // [d][key], swizzled
  __shared__ __attribute__((aligned(16))) unsigned short Pl[4][16*64];   // per-wave P, swizzled

  int bid = blockIdx.x;
  int wg = ((bid & 7) << 8) | (bid >> 3);   // XCD-contiguous chunks of 256
  int qb = wg & 15, h = (wg >> 4) & 15, n = wg >> 8;

  int tid = threadIdx.x, wid = tid >> 6, lane = tid & 63, lg = lane >> 4, lc = lane & 15;
  int qbase = qb * 64 + wid * 16;

  const unsigned short* Kh = Kb  + ((size_t)(n*16 + h)) * 1024 * 64;
  const unsigned short* Vh = Vtg + ((size_t)(n*16 + h)) * 64 * 1024;
  const unsigned* bp0 = bits + (size_t)(n*1024 + qbase + lg*4) * 32;

  // Q fragment from original fp32 layout (one-time)
  bf16x8 qf[2];
  {
    const float* qp = Q + (size_t)(n*1024 + qbase + lc) * 1024 + h*64;
    #pragma unroll
    for (int c = 0; c < 2; ++c){
      float4 a0 = *reinterpret_cast<const float4*>(qp + c*32 + lg*8);
      float4 a1 = *reinterpret_cast<const float4*>(qp + c*32 + lg*8 + 4);
      bfpack pk;
      pk.u[0] = pk2(a0.x,a0.y); pk.u[1] = pk2(a0.z,a0.w);
      pk.u[2] = pk2(a1.x,a1.y); pk.u[3] = pk2(a1.z,a1.w);
      qf[c] = pk.v;
    }
  }

  // staging slots: slot s -> LDS byte 16s == SWZ(row=s>>3, col=(s&7)*16 ^ ((row&7)<<4))
  const int s0 = tid, s1 = tid + 256;
  const int r0 = s0 >> 3, c0 = ((s0 & 7) * 16) ^ ((r0 & 7) << 4);
  const int r1 = s1 >> 3, c1 = ((s1 & 7) * 16) ^ ((r1 & 7) << 4);

#define STAGE(KB, BUF) do { \
    gld16((const char*)Kh + ((size_t)((KB)*64 + r0) * 128 + c0), (char*)Kt[BUF] + s0*16); \
    gld16((const char*)Kh + ((size_t)((KB)*64 + r1) * 128 + c1), (char*)Kt[BUF] + s1*16); \
    gld16((const char*)Vh + ((size_t)r0 * 2048 + (KB)*128 + c0), (char*)Vt[BUF] + s0*16); \
    gld16((const char*)Vh + ((size_t)r1 * 2048 + (KB)*128 + c1), (char*)Vt[BUF] + s1*16); \
  } while(0)

#define LOADW(KB, W) do { \
    const unsigned* bp_ = bp0 + (KB)*2; \
    _Pragma("unroll") \
    for (int r_ = 0; r_ < 4; ++r_){ W[r_][0] = bp_[r_*32]; W[r_][1] = bp_[r_*32 + 1]; } \
  } while(0)

  f32x4 acc[4];
  for (int i = 0; i < 4; ++i) acc[i] = (f32x4){0.f,0.f,0.f,0.f};
  float lsum[4] = {0.f,0.f,0.f,0.f};
  const float c2 = 0.045084220027780106f;   // log2(e)/32

  unsigned wcur[4][2], wnxt[4][2];
  STAGE(0, 0);
  LOADW(0, wcur);
  int cur = 0;

  for (int kb = 0; kb < 16; ++kb){
    __syncthreads();                      // drains vmcnt -> buf[cur] ready; prev reads done
    if (kb < 15){
      STAGE(kb + 1, cur ^ 1);             // next K/V tile in flight under this tile's compute
      LOADW(kb + 1, wnxt);                // next mask words in flight too (full-tile cover)
    }

    // ---- S = Q . K^T ----
    f32x4 S[4];
    #pragma unroll
    for (int t = 0; t < 4; ++t) S[t] = (f32x4){0.f,0.f,0.f,0.f};
    __builtin_amdgcn_s_setprio(1);
    #pragma unroll
    for (int t = 0; t < 4; ++t)
      #pragma unroll
      for (int c = 0; c < 2; ++c){
        bf16x8 kf = *reinterpret_cast<const bf16x8*>((const char*)Kt[cur] + SWZ(t*16 + lc, lg*16 + c*64));
        S[t] = __builtin_amdgcn_mfma_f32_16x16x32_bf16(qf[c], kf, S[t], 0, 0, 0);
      }
    __builtin_amdgcn_s_setprio(0);

    // ---- static softmax: p = masked ? 1.0 : exp2(S*log2e/32) ----
    float p[4][4];
    #pragma unroll
    for (int t = 0; t < 4; ++t){
      int bitidx = ((t & 1) << 4) + lc;
      #pragma unroll
      for (int r = 0; r < 4; ++r){
        bool mk = (wcur[r][t>>1] >> bitidx) & 1u;
        p[t][r] = mk ? exp2f(S[t][r] * c2) : 1.0f;
      }
    }
    #pragma unroll
    for (int r = 0; r < 4; ++r)
      lsum[r] += (p[0][r] + p[1][r]) + (p[2][r] + p[3][r]);

    // ---- P -> bf16 (cvt_pk) -> per-wave LDS (A-fragment relayout) ----
    unsigned short* pl = &Pl[wid][0];
    #pragma unroll
    for (int t = 0; t < 4; ++t){
      unsigned w01 = pk2(p[t][0], p[t][1]);
      unsigned w23 = pk2(p[t][2], p[t][3]);
      int colb = (t*16 + lc)*2;
      *(unsigned short*)((char*)pl + SWZ(lg*4 + 0, colb)) = (unsigned short)w01;
      *(unsigned short*)((char*)pl + SWZ(lg*4 + 1, colb)) = (unsigned short)(w01 >> 16);
      *(unsigned short*)((char*)pl + SWZ(lg*4 + 2, colb)) = (unsigned short)w23;
      *(unsigned short*)((char*)pl + SWZ(lg*4 + 3, colb)) = (unsigned short)(w23 >> 16);
    }

    // ---- O += P . V ----
    __builtin_amdgcn_s_setprio(1);
    #pragma unroll
    for (int kc = 0; kc < 2; ++kc){
      bf16x8 af = *reinterpret_cast<const bf16x8*>((const char*)pl + SWZ(lc, lg*16 + kc*64));
      #pragma unroll
      for (int t2 = 0; t2 < 4; ++t2){
        bf16x8 vf = *reinterpret_cast<const bf16x8*>((const char*)Vt[cur] + SWZ(t2*16 + lc, lg*16 + kc*64));
        acc[t2] = __builtin_amdgcn_mfma_f32_16x16x32_bf16(af, vf, acc[t2], 0, 0, 0);
      }
    }
    __builtin_amdgcn_s_setprio(0);

    // rotate mask-word double buffer
    #pragma unroll
    for (int r = 0; r < 4; ++r){ wcur[r][0] = wnxt[r][0]; wcur[r][1] = wnxt[r][1]; }
    cur ^= 1;
  }
#undef STAGE
#undef LOADW

  // ---- final sum-reduce across the 16-lane group, normalize, store (n,q,h,d) ----
  #pragma unroll
  for (int r = 0; r < 4; ++r){
    float s = lsum[r];
    for (int d = 1; d < 16; d <<= 1) s += __shfl_xor(s, d, 64);
    float inv = 1.0f / s;
    size_t qg = (size_t)(n*1024 + qbase + lg*4 + r);
    unsigned short* op = Obf + (qg * 16 + h) * 64;
    unsigned w01 = pk2(acc[0][r]*inv, acc[1][r]*inv);
    unsigned w23 = pk2(acc[2][r]*inv, acc[3][r]*inv);
    op[0*16 + lc] = (unsigned short)w01;
    op[1*16 + lc] = (unsigned short)(w01 >> 16);
    op[2*16 + lc] = (unsigned short)w23;
    op[3*16 + lc] = (unsigned short)(w23 >> 16);
  }
}

// ---------------- out = O @ W^T + b  (8192x1024x1024 bf16 GEMM, DMA-staged, dbuf) ----------------
__global__ __launch_bounds__(256) void out_gemm_kernel(
    const unsigned short* __restrict__ A, const unsigned short* __restrict__ B,
    const float* __restrict__ bias, float* __restrict__ out)
{
  __shared__ __attribute__((aligned(16))) unsigned short As[2][128*64];
  __shared__ __attribute__((aligned(16))) unsigned short Bs[2][128*64];

  int mb = blockIdx.x;     // 64
  int nb = blockIdx.y;     // 8
  int tid = threadIdx.x, wid = tid >> 6, lane = tid & 63, lg = lane >> 4, lc = lane & 15;
  int wr = wid >> 1, wc = wid & 1;

  int rr[4], cc[4];
  #pragma unroll
  for (int i = 0; i < 4; ++i){
    int s = tid + 256*i;
    rr[i] = s >> 3;
    cc[i] = ((s & 7) * 16) ^ ((rr[i] & 7) << 4);
  }

#define GSTAGE(KB, BUF) do { \
    _Pragma("unroll") \
    for (int i = 0; i < 4; ++i){ \
      int s = tid + 256*i; \
      gld16((const char*)A + ((size_t)(mb*128 + rr[i]) * 1024 + (KB)*64) * 2 + cc[i], (char*)As[BUF] + s*16); \
      gld16((const char*)B + ((size_t)(nb*128 + rr[i]) * 1024 + (KB)*64) * 2 + cc[i], (char*)Bs[BUF] + s*16); \
    } \
  } while(0)

  f32x4 acc[4][4];
  for (int m = 0; m < 4; ++m)
    for (int nn2 = 0; nn2 < 4; ++nn2) acc[m][nn2] = (f32x4){0.f,0.f,0.f,0.f};

  GSTAGE(0, 0);
  int cur = 0;

  for (int kb = 0; kb < 16; ++kb){
    __syncthreads();
    if (kb < 15) GSTAGE(kb + 1, cur ^ 1);
    #pragma unroll
    for (int kc = 0; kc < 2; ++kc){
      bf16x8 af[4], bfr[4];
      #pragma unroll
      for (int m = 0; m < 4; ++m)
        af[m] = *reinterpret_cast<const bf16x8*>((const char*)As[cur] + SWZ(wr*64 + m*16 + lc, kc*64 + lg*16));
      #pragma unroll
      for (int nn2 = 0; nn2 < 4; ++nn2)
        bfr[nn2] = *reinterpret_cast<const bf16x8*>((const char*)Bs[cur] + SWZ(wc*64 + nn2*16 + lc, kc*64 + lg*16));
      __builtin_amdgcn_s_setprio(1);
      #pragma unroll
      for (int m = 0; m < 4; ++m)
        #pragma unroll
        for (int nn2 = 0; nn2 < 4; ++nn2)
          acc[m][nn2] = __builtin_amdgcn_mfma_f32_16x16x32_bf16(af[m], bfr[nn2], acc[m][nn2], 0, 0, 0);
      __builtin_amdgcn_s_setprio(0);
    }
    cur ^= 1;
  }
#undef GSTAGE

  for (int nn2 = 0; nn2 < 4; ++nn2){
    int col = nb*128 + wc*64 + nn2*16 + lc;
    float bv = bias[col];
    for (int m = 0; m < 4; ++m){
      int rowb = mb*128 + wr*64 + m*16 + lg*4;
      for (int r = 0; r < 4; ++r)
        out[(size_t)(rowb + r) * 1024 + col] = acc[m][nn2][r] + bv;
    }
  }
}

extern "C" void kernel_launch(void* const* d_in, const int* in_sizes, int n_in,
                              void* d_out, int out_size, void* d_ws, size_t ws_size,
                              hipStream_t stream) {
  const float* V  = (const float*)d_in[0];
  const float* K  = (const float*)d_in[1];
  const float* Q  = (const float*)d_in[2];
  const int* mask = (const int*)d_in[3];
  const float* W  = (const float*)d_in[4];
  const float* b  = (const float*)d_in[5];
  float* out = (float*)d_out;

  char* ws = (char*)d_ws;
  unsigned* bits       = (unsigned*)ws;                      // 1 MB
  unsigned short* Wb   = (unsigned short*)(ws + (1u<<20));   // 2 MB
  unsigned short* Obf  = (unsigned short*)(ws + (3u<<20));   // 16 MB
  unsigned short* Vtg  = (unsigned short*)(ws + (19u<<20));  // 16 MB
  // Kb lives in d_out (32 MB, fully overwritten by the final GEMM afterwards)
  unsigned short* Kb   = (unsigned short*)d_out;             // 16 MB

  prep_kernel<<<9216, 256, 0, stream>>>(mask, (unsigned short*)bits, W, Wb, K, Kb, V, Vtg);
  attn_kernel<<<2048, 256, 0, stream>>>(Q, Kb, Vtg, bits, Obf);
  dim3 g(64, 8);
  out_gemm_kernel<<<g, 256, 0, stream>>>(Obf, Wb, b, out);
}

// Round 16
// 122.409 us; speedup vs baseline: 1.1214x; 1.1214x over previous
//
#include <hip/hip_runtime.h>
#include <hip/hip_bf16.h>

typedef __attribute__((ext_vector_type(8))) short bf16x8;
typedef __attribute__((ext_vector_type(4))) float f32x4;

// Swizzled byte address for 128-byte rows: XOR row bits into the 16B-slot index.
#define SWZ(row, byteofs) (((row)*128) + ((byteofs) ^ (((row)&7)<<4)))

__device__ __forceinline__ unsigned pk2(float a, float b){
  __hip_bfloat162 h = __float22bfloat162_rn(make_float2(a, b));   // v_cvt_pk_bf16_f32
  unsigned u; __builtin_memcpy(&u, &h, 4);
  return u;
}

__device__ __forceinline__ void gld16(const void* g, void* l){
  __builtin_amdgcn_global_load_lds((const __attribute__((address_space(1))) void*)g,
                                   (__attribute__((address_space(3))) void*)l, 16, 0, 0);
}

union bfpack { bf16x8 v; unsigned u[4]; uint4 q; };

// ================= fused prep kernel =================
// sections by blockIdx.x:
//   [0,2048)      mask -> bitmask (16 keys/thread, int4x4 loads, u16 store)
//   [2048,3072)   W fp32 -> bf16
//   [3072,7168)   K permute (n,L,h*64) f32 -> (n,h,L,64) bf16
//   [7168,9216)   V permute+transpose -> (n,h,64,L) bf16
__global__ __launch_bounds__(256) void prep_kernel(
    const int* __restrict__ mask, unsigned short* __restrict__ bits16,
    const float* __restrict__ W, unsigned short* __restrict__ Wb,
    const float* __restrict__ Ksrc, unsigned short* __restrict__ Kb,
    const float* __restrict__ Vsrc, unsigned short* __restrict__ Vtg)
{
  __shared__ __attribute__((aligned(16))) unsigned short T[64*64];
  int bid = blockIdx.x, tid = threadIdx.x;

  if (bid < 2048){
    // ---- mask bits: thread i covers 16 consecutive mask ints ----
    size_t i = (size_t)bid * 256 + tid;
    const int4* mp = reinterpret_cast<const int4*>(mask) + i * 4;
    int4 a = mp[0], b = mp[1], c = mp[2], d = mp[3];
    unsigned m = 0;
    m |= (a.x!=0) ? 1u<<0 : 0;  m |= (a.y!=0) ? 1u<<1 : 0;
    m |= (a.z!=0) ? 1u<<2 : 0;  m |= (a.w!=0) ? 1u<<3 : 0;
    m |= (b.x!=0) ? 1u<<4 : 0;  m |= (b.y!=0) ? 1u<<5 : 0;
    m |= (b.z!=0) ? 1u<<6 : 0;  m |= (b.w!=0) ? 1u<<7 : 0;
    m |= (c.x!=0) ? 1u<<8 : 0;  m |= (c.y!=0) ? 1u<<9 : 0;
    m |= (c.z!=0) ? 1u<<10 : 0; m |= (c.w!=0) ? 1u<<11 : 0;
    m |= (d.x!=0) ? 1u<<12 : 0; m |= (d.y!=0) ? 1u<<13 : 0;
    m |= (d.z!=0) ? 1u<<14 : 0; m |= (d.w!=0) ? 1u<<15 : 0;
    bits16[i] = (unsigned short)m;
  } else if (bid < 3072){
    // ---- W convert ----
    int i = (bid - 2048) * 256 + tid;
    float4 f = reinterpret_cast<const float4*>(W)[i];
    uint2 o = make_uint2(pk2(f.x, f.y), pk2(f.z, f.w));
    reinterpret_cast<uint2*>(Wb)[i] = o;
  } else if (bid < 7168){
    // ---- K permute ----
    int w = (bid - 3072) * 4 + (tid >> 6);
    int lane = tid & 63;
    int n = w >> 11, h = (w >> 7) & 15, l8 = w & 127;
    int l = l8 * 8 + (lane >> 3);
    int dch = (lane & 7) * 8;
    const float* sp = Ksrc + ((size_t)n * 1024 + l) * 1024 + h * 64 + dch;
    float4 a = *reinterpret_cast<const float4*>(sp);
    float4 b = *reinterpret_cast<const float4*>(sp + 4);
    uint4 o = make_uint4(pk2(a.x,a.y), pk2(a.z,a.w), pk2(b.x,b.y), pk2(b.z,b.w));
    *reinterpret_cast<uint4*>(Kb + (((size_t)n * 16 + h) * 1024 + l) * 64 + dch) = o;
  } else {
    // ---- V permute + transpose ----
    int vb = bid - 7168;                  // 2048 = n(8) x h(16) x ltile(16)
    int n = vb >> 8, h = (vb >> 4) & 15, l0 = (vb & 15) * 64;
    {
      int l = tid >> 2, dseg = tid & 3;
      const float* sp = Vsrc + ((size_t)n * 1024 + l0 + l) * 1024 + h * 64 + dseg * 16;
      float4 f0 = *reinterpret_cast<const float4*>(sp + 0);
      float4 f1 = *reinterpret_cast<const float4*>(sp + 4);
      float4 f2 = *reinterpret_cast<const float4*>(sp + 8);
      float4 f3 = *reinterpret_cast<const float4*>(sp + 12);
      uint4 lo = make_uint4(pk2(f0.x,f0.y), pk2(f0.z,f0.w), pk2(f1.x,f1.y), pk2(f1.z,f1.w));
      uint4 hi = make_uint4(pk2(f2.x,f2.y), pk2(f2.z,f2.w), pk2(f3.x,f3.y), pk2(f3.z,f3.w));
      *reinterpret_cast<uint4*>((char*)T + SWZ(l, dseg*32))      = lo;
      *reinterpret_cast<uint4*>((char*)T + SWZ(l, dseg*32 + 16)) = hi;
    }
    __syncthreads();
    {
      int d = tid >> 2, lseg = tid & 3;
      for (int j = 0; j < 2; ++j){
        bf16x8 wv;
        #pragma unroll
        for (int i = 0; i < 8; ++i){
          int l = lseg*16 + j*8 + i;      // l&7 == i (static per unrolled i)
          wv[i] = *(const short*)((const char*)T + (size_t)l*128 + ((d*2) ^ (i<<4)));
        }
        *reinterpret_cast<bf16x8*>(Vtg + (((size_t)n * 16 + h) * 64 + d) * 1024 + l0 + lseg*16 + j*8) = wv;
      }
    }
  }
}

// ---- flash attention (champion: dbuf DMA staging, static softmax, lsum epilogue) ----
// grid: 2048 blocks = (n:8) x (h:16) x (qb:16), 256 threads (4 waves x 16 q-rows)
__global__ __launch_bounds__(256) void attn_kernel(
    const float* __restrict__ Q, const unsigned short* __restrict__ Kb,
    const unsigned short* __restrict__ Vtg, const unsigned* __restrict__ bits,
    unsigned short* __restrict__ Obf)
{
  __shared__ __attribute__((aligned(16))) unsigned short Kt[2][64*64];   // [key][d], swizzled
  __shared__ __attribute__((aligned(16))) unsigned short Vt[2][64*64];   // [d][key], swizzled
  __shared__ __attribute__((aligned(16))) unsigned short Pl[4][16*64];   // per-wave P, swizzled

  int bid = blockIdx.x;
  int wg = ((bid & 7) << 8) | (bid >> 3);   // XCD-contiguous chunks of 256
  int qb = wg & 15, h = (wg >> 4) & 15, n = wg >> 8;

  int tid = threadIdx.x, wid = tid >> 6, lane = tid & 63, lg = lane >> 4, lc = lane & 15;
  int qbase = qb * 64 + wid * 16;

  const unsigned short* Kh = Kb  + ((size_t)(n*16 + h)) * 1024 * 64;
  const unsigned short* Vh = Vtg + ((size_t)(n*16 + h)) * 64 * 1024;

  // Q fragment from original fp32 layout (one-time)
  bf16x8 qf[2];
  {
    const float* qp = Q + (size_t)(n*1024 + qbase + lc) * 1024 + h*64;
    #pragma unroll
    for (int c = 0; c < 2; ++c){
      float4 a0 = *reinterpret_cast<const float4*>(qp + c*32 + lg*8);
      float4 a1 = *reinterpret_cast<const float4*>(qp + c*32 + lg*8 + 4);
      bfpack pk;
      pk.u[0] = pk2(a0.x,a0.y); pk.u[1] = pk2(a0.z,a0.w);
      pk.u[2] = pk2(a1.x,a1.y); pk.u[3] = pk2(a1.z,a1.w);
      qf[c] = pk.v;
    }
  }

  // staging slots: slot s -> LDS byte 16s == SWZ(row=s>>3, col=(s&7)*16 ^ ((row&7)<<4))
  const int s0 = tid, s1 = tid + 256;
  const int r0 = s0 >> 3, c0 = ((s0 & 7) * 16) ^ ((r0 & 7) << 4);
  const int r1 = s1 >> 3, c1 = ((s1 & 7) * 16) ^ ((r1 & 7) << 4);

#define STAGE(KB, BUF) do { \
    gld16((const char*)Kh + ((size_t)((KB)*64 + r0) * 128 + c0), (char*)Kt[BUF] + s0*16); \
    gld16((const char*)Kh + ((size_t)((KB)*64 + r1) * 128 + c1), (char*)Kt[BUF] + s1*16); \
    gld16((const char*)Vh + ((size_t)r0 * 2048 + (KB)*128 + c0), (char*)Vt[BUF] + s0*16); \
    gld16((const char*)Vh + ((size_t)r1 * 2048 + (KB)*128 + c1), (char*)Vt[BUF] + s1*16); \
  } while(0)

  f32x4 acc[4];
  for (int i = 0; i < 4; ++i) acc[i] = (f32x4){0.f,0.f,0.f,0.f};
  float lsum[4] = {0.f,0.f,0.f,0.f};
  const float scale = 0.03125f;   // 1/sqrt(1024)

  STAGE(0, 0);
  int cur = 0;

  for (int kb = 0; kb < 16; ++kb){
    __syncthreads();                      // drains vmcnt -> buf[cur] ready; prev reads done
    if (kb < 15) STAGE(kb + 1, cur ^ 1);  // in flight under this tile's compute

    // mask words
    unsigned words[4][2];
    {
      const unsigned* bp = bits + (size_t)(n*1024 + qbase + lg*4) * 32 + kb*2;
      #pragma unroll
      for (int r = 0; r < 4; ++r){ words[r][0] = bp[r*32]; words[r][1] = bp[r*32 + 1]; }
    }

    // ---- S = Q . K^T ----
    f32x4 S[4];
    #pragma unroll
    for (int t = 0; t < 4; ++t) S[t] = (f32x4){0.f,0.f,0.f,0.f};
    __builtin_amdgcn_s_setprio(1);
    #pragma unroll
    for (int t = 0; t < 4; ++t)
      #pragma unroll
      for (int c = 0; c < 2; ++c){
        bf16x8 kf = *reinterpret_cast<const bf16x8*>((const char*)Kt[cur] + SWZ(t*16 + lc, lg*16 + c*64));
        S[t] = __builtin_amdgcn_mfma_f32_16x16x32_bf16(qf[c], kf, S[t], 0, 0, 0);
      }
    __builtin_amdgcn_s_setprio(0);

    // ---- static softmax: p = masked ? 1.0 : exp(S/32) ----
    float p[4][4];
    #pragma unroll
    for (int t = 0; t < 4; ++t){
      int bitidx = ((t & 1) << 4) + lc;
      #pragma unroll
      for (int r = 0; r < 4; ++r){
        bool mk = (words[r][t>>1] >> bitidx) & 1u;
        p[t][r] = mk ? __expf(S[t][r] * scale) : 1.0f;
      }
    }
    #pragma unroll
    for (int r = 0; r < 4; ++r)
      lsum[r] += (p[0][r] + p[1][r]) + (p[2][r] + p[3][r]);

    // ---- P -> bf16 (cvt_pk) -> per-wave LDS (A-fragment relayout) ----
    unsigned short* pl = &Pl[wid][0];
    #pragma unroll
    for (int t = 0; t < 4; ++t){
      unsigned w01 = pk2(p[t][0], p[t][1]);
      unsigned w23 = pk2(p[t][2], p[t][3]);
      int colb = (t*16 + lc)*2;
      *(unsigned short*)((char*)pl + SWZ(lg*4 + 0, colb)) = (unsigned short)w01;
      *(unsigned short*)((char*)pl + SWZ(lg*4 + 1, colb)) = (unsigned short)(w01 >> 16);
      *(unsigned short*)((char*)pl + SWZ(lg*4 + 2, colb)) = (unsigned short)w23;
      *(unsigned short*)((char*)pl + SWZ(lg*4 + 3, colb)) = (unsigned short)(w23 >> 16);
    }

    // ---- O += P . V ----
    __builtin_amdgcn_s_setprio(1);
    #pragma unroll
    for (int kc = 0; kc < 2; ++kc){
      bf16x8 af = *reinterpret_cast<const bf16x8*>((const char*)pl + SWZ(lc, lg*16 + kc*64));
      #pragma unroll
      for (int t2 = 0; t2 < 4; ++t2){
        bf16x8 vf = *reinterpret_cast<const bf16x8*>((const char*)Vt[cur] + SWZ(t2*16 + lc, lg*16 + kc*64));
        acc[t2] = __builtin_amdgcn_mfma_f32_16x16x32_bf16(af, vf, acc[t2], 0, 0, 0);
      }
    }
    __builtin_amdgcn_s_setprio(0);
    cur ^= 1;
  }
#undef STAGE

  // ---- final sum-reduce across the 16-lane group, normalize, store (n,q,h,d) ----
  #pragma unroll
  for (int r = 0; r < 4; ++r){
    float s = lsum[r];
    for (int d = 1; d < 16; d <<= 1) s += __shfl_xor(s, d, 64);
    float inv = 1.0f / s;
    size_t qg = (size_t)(n*1024 + qbase + lg*4 + r);
    unsigned short* op = Obf + (qg * 16 + h) * 64;
    unsigned w01 = pk2(acc[0][r]*inv, acc[1][r]*inv);
    unsigned w23 = pk2(acc[2][r]*inv, acc[3][r]*inv);
    op[0*16 + lc] = (unsigned short)w01;
    op[1*16 + lc] = (unsigned short)(w01 >> 16);
    op[2*16 + lc] = (unsigned short)w23;
    op[3*16 + lc] = (unsigned short)(w23 >> 16);
  }
}

// ---------------- out = O @ W^T + b  (8192x1024x1024 bf16 GEMM, DMA-staged, dbuf) ----------------
__global__ __launch_bounds__(256) void out_gemm_kernel(
    const unsigned short* __restrict__ A, const unsigned short* __restrict__ B,
    const float* __restrict__ bias, float* __restrict__ out)
{
  __shared__ __attribute__((aligned(16))) unsigned short As[2][128*64];
  __shared__ __attribute__((aligned(16))) unsigned short Bs[2][128*64];

  int mb = blockIdx.x;     // 64
  int nb = blockIdx.y;     // 8
  int tid = threadIdx.x, wid = tid >> 6, lane = tid & 63, lg = lane >> 4, lc = lane & 15;
  int wr = wid >> 1, wc = wid & 1;

  int rr[4], cc[4];
  #pragma unroll
  for (int i = 0; i < 4; ++i){
    int s = tid + 256*i;
    rr[i] = s >> 3;
    cc[i] = ((s & 7) * 16) ^ ((rr[i] & 7) << 4);
  }

#define GSTAGE(KB, BUF) do { \
    _Pragma("unroll") \
    for (int i = 0; i < 4; ++i){ \
      int s = tid + 256*i; \
      gld16((const char*)A + ((size_t)(mb*128 + rr[i]) * 1024 + (KB)*64) * 2 + cc[i], (char*)As[BUF] + s*16); \
      gld16((const char*)B + ((size_t)(nb*128 + rr[i]) * 1024 + (KB)*64) * 2 + cc[i], (char*)Bs[BUF] + s*16); \
    } \
  } while(0)

  f32x4 acc[4][4];
  for (int m = 0; m < 4; ++m)
    for (int nn2 = 0; nn2 < 4; ++nn2) acc[m][nn2] = (f32x4){0.f,0.f,0.f,0.f};

  GSTAGE(0, 0);
  int cur = 0;

  for (int kb = 0; kb < 16; ++kb){
    __syncthreads();
    if (kb < 15) GSTAGE(kb + 1, cur ^ 1);
    #pragma unroll
    for (int kc = 0; kc < 2; ++kc){
      bf16x8 af[4], bfr[4];
      #pragma unroll
      for (int m = 0; m < 4; ++m)
        af[m] = *reinterpret_cast<const bf16x8*>((const char*)As[cur] + SWZ(wr*64 + m*16 + lc, kc*64 + lg*16));
      #pragma unroll
      for (int nn2 = 0; nn2 < 4; ++nn2)
        bfr[nn2] = *reinterpret_cast<const bf16x8*>((const char*)Bs[cur] + SWZ(wc*64 + nn2*16 + lc, kc*64 + lg*16));
      __builtin_amdgcn_s_setprio(1);
      #pragma unroll
      for (int m = 0; m < 4; ++m)
        #pragma unroll
        for (int nn2 = 0; nn2 < 4; ++nn2)
          acc[m][nn2] = __builtin_amdgcn_mfma_f32_16x16x32_bf16(af[m], bfr[nn2], acc[m][nn2], 0, 0, 0);
      __builtin_amdgcn_s_setprio(0);
    }
    cur ^= 1;
  }
#undef GSTAGE

  for (int nn2 = 0; nn2 < 4; ++nn2){
    int col = nb*128 + wc*64 + nn2*16 + lc;
    float bv = bias[col];
    for (int m = 0; m < 4; ++m){
      int rowb = mb*128 + wr*64 + m*16 + lg*4;
      for (int r = 0; r < 4; ++r)
        out[(size_t)(rowb + r) * 1024 + col] = acc[m][nn2][r] + bv;
    }
  }
}

extern "C" void kernel_launch(void* const* d_in, const int* in_sizes, int n_in,
                              void* d_out, int out_size, void* d_ws, size_t ws_size,
                              hipStream_t stream) {
  const float* V  = (const float*)d_in[0];
  const float* K  = (const float*)d_in[1];
  const float* Q  = (const float*)d_in[2];
  const int* mask = (const int*)d_in[3];
  const float* W  = (const float*)d_in[4];
  const float* b  = (const float*)d_in[5];
  float* out = (float*)d_out;

  char* ws = (char*)d_ws;
  unsigned* bits       = (unsigned*)ws;                      // 1 MB
  unsigned short* Wb   = (unsigned short*)(ws + (1u<<20));   // 2 MB
  unsigned short* Obf  = (unsigned short*)(ws + (3u<<20));   // 16 MB
  unsigned short* Vtg  = (unsigned short*)(ws + (19u<<20));  // 16 MB
  // Kb lives in d_out (32 MB, fully overwritten by the final GEMM afterwards)
  unsigned short* Kb   = (unsigned short*)d_out;             // 16 MB

  prep_kernel<<<9216, 256, 0, stream>>>(mask, (unsigned short*)bits, W, Wb, K, Kb, V, Vtg);
  attn_kernel<<<2048, 256, 0, stream>>>(Q, Kb, Vtg, bits, Obf);
  dim3 g(64, 8);
  out_gemm_kernel<<<g, 256, 0, stream>>>(Obf, Wb, b, out);
}